// Round 6
// baseline (1250.758 us; speedup 1.0000x reference)
//
#include <hip/hip_runtime.h>
#include <hip/hip_bf16.h>
#include <cstddef>

#define T_SEQ 1024
#define D_MODEL 512

typedef __attribute__((ext_vector_type(8))) __bf16 bf16x8;
typedef __attribute__((ext_vector_type(4))) float f32x4;
typedef __attribute__((ext_vector_type(16))) float f32x16;
typedef __attribute__((ext_vector_type(8))) unsigned short u16x8;
typedef __attribute__((ext_vector_type(4))) unsigned int u32x4;

typedef const unsigned int __attribute__((address_space(1)))* gas1_t;
typedef unsigned int __attribute__((address_space(3)))* las3_t;

__device__ __forceinline__ void gload_lds16(const void* g, void* l) {
  __builtin_amdgcn_global_load_lds((gas1_t)g, (las3_t)l, 16, 0, 0);
}

__device__ __forceinline__ float bf2f(unsigned short u) {
  return __uint_as_float(((unsigned)u) << 16);
}
__device__ __forceinline__ unsigned short f2bf(float f) {
  __hip_bfloat16 h = __float2bfloat16(f);
  return *(unsigned short*)&h;
}

#define CVTPK(dst, a, b) \
  asm("v_cvt_pk_bf16_f32 %0, %1, %2" : "=v"(dst) : "v"(a), "v"(b))

// exchange lane halves between two dwords (for global attn P redistribution)
__device__ __forceinline__ void swap32(unsigned& a, unsigned& b, int lane) {
  const unsigned ax = __shfl_xor(a, 32);
  const unsigned bx = __shfl_xor(b, 32);
  const bool lo = lane < 32;
  const unsigned na = lo ? a : bx;
  const unsigned nb = lo ? ax : b;
  a = na; b = nb;
}

// =====================================================================
// Cast fp32 -> bf16 (each thread 8 elems)
// =====================================================================
__global__ __launch_bounds__(256)
void cast_x_kernel(const float* __restrict__ in, __hip_bfloat16* __restrict__ out) {
  const int i = (blockIdx.x * 256 + threadIdx.x) * 8;
  const float4 a = *(const float4*)(in + i);
  const float4 b = *(const float4*)(in + i + 4);
  u16x8 o;
  o[0] = f2bf(a.x); o[1] = f2bf(a.y); o[2] = f2bf(a.z); o[3] = f2bf(a.w);
  o[4] = f2bf(b.x); o[5] = f2bf(b.y); o[6] = f2bf(b.z); o[7] = f2bf(b.w);
  *(u16x8*)(out + i) = o;
}

// =====================================================================
// ALL weight prep in ONE dispatch. z = blockIdx.y selects matrix:
//  0-2 loc_wq (T), 3-5 loc_wk (T), 6-8 loc_wv (T), 9 g_wq, 10 g_wk,
//  11 g_wv (T), 12-15 out_w (T), 16-18 loc_wo (plain), 19 g_wo (plain).
// (T) = transpose+cast into WT[z]; plain = cast only.
// =====================================================================
__global__ __launch_bounds__(256)
void prep_weights_kernel(const float* __restrict__ loc_wq, const float* __restrict__ loc_wk,
                         const float* __restrict__ loc_wv, const float* __restrict__ g_wq,
                         const float* __restrict__ g_wk, const float* __restrict__ g_wv,
                         const float* __restrict__ out_w, const float* __restrict__ loc_wo,
                         const float* __restrict__ g_wo, __hip_bfloat16* __restrict__ WT) {
  __shared__ float tile[32][33];
  const size_t MS = (size_t)512 * 512;
  const int z = blockIdx.y;
  const float* src;
  bool tr = true;
  if (z < 3)       src = loc_wq + (size_t)z * MS;
  else if (z < 6)  src = loc_wk + (size_t)(z - 3) * MS;
  else if (z < 9)  src = loc_wv + (size_t)(z - 6) * MS;
  else if (z == 9)  src = g_wq;
  else if (z == 10) src = g_wk;
  else if (z == 11) src = g_wv;
  else if (z < 16) src = out_w + (size_t)(z - 12) * MS;
  else if (z < 19) { src = loc_wo + (size_t)(z - 16) * MS; tr = false; }
  else             { src = g_wo; tr = false; }
  __hip_bfloat16* dst = WT + (size_t)z * MS;

  const int tk = (blockIdx.x & 15) * 32;
  const int tn = (blockIdx.x >> 4) * 32;
  const int t = threadIdx.x;
  const int r = t >> 3, c4 = (t & 7) * 4;
  const float4 v = *(const float4*)(src + (size_t)(tk + r) * 512 + tn + c4);
  if (tr) {
    tile[r][c4 + 0] = v.x; tile[r][c4 + 1] = v.y;
    tile[r][c4 + 2] = v.z; tile[r][c4 + 3] = v.w;
    __syncthreads();
    ushort4 o;
    o.x = f2bf(tile[c4 + 0][r]); o.y = f2bf(tile[c4 + 1][r]);
    o.z = f2bf(tile[c4 + 2][r]); o.w = f2bf(tile[c4 + 3][r]);
    *(ushort4*)(dst + (size_t)(tn + r) * 512 + tk + c4) = o;
  } else {
    ushort4 o;
    o.x = f2bf(v.x); o.y = f2bf(v.y); o.z = f2bf(v.z); o.w = f2bf(v.w);
    *(ushort4*)(dst + (size_t)(tk + r) * 512 + tn + c4) = o;
  }
}

// =====================================================================
// Fused bias: bfused[z][n] = bo_z @ out_w[z*512..] (+ out_b for z==0).
// =====================================================================
__global__ __launch_bounds__(256)
void bias_fuse_kernel(const float* __restrict__ loc_bo, const float* __restrict__ g_bo,
                      const float* __restrict__ out_w, const float* __restrict__ out_b,
                      float* __restrict__ bfused) {
  const int z = blockIdx.y;
  const int n = blockIdx.x * 256 + threadIdx.x;
  const float* bo = (z < 3) ? loc_bo + z * 512 : g_bo;
  const float* W = out_w + (size_t)z * 512 * 512;
  float acc = (z == 0) ? out_b[n] : 0.f;
  for (int m = 0; m < 512; ++m)
    acc = fmaf(bo[m], W[(size_t)m * 512 + n], acc);
  bfused[z * 512 + n] = acc;
}

// =====================================================================
// MFMA GEMM core: BM=64 BN=128 BK=32. ACCUMULATES into acc (caller zeros).
// =====================================================================
__device__ __forceinline__ void gemm_core_512(
    const __hip_bfloat16* __restrict__ A, const __hip_bfloat16* __restrict__ BT,
    __hip_bfloat16* As, __hip_bfloat16* Bs, int row0, int col0, f32x4 acc[2][4]) {
  const int tid = threadIdx.x;
  const int wv = tid >> 6, lane = tid & 63;
  const int g = lane >> 4, r16 = lane & 15;
  const int wm = wv >> 1, wn = wv & 1;
  const char* Ab = (const char*)A;
  const char* Bb = (const char*)BT;
  for (int k0 = 0; k0 < 512; k0 += 32) {
    {
      const int row = tid >> 2, off = (tid & 3) << 4;
      gload_lds16(Ab + (size_t)(row0 + row) * 1024 + k0 * 2 + off,
                  (char*)As + (wv << 10));
    }
    {
      const int row = tid >> 2, off = (tid & 3) << 4;
      gload_lds16(Bb + (size_t)(col0 + row) * 1024 + k0 * 2 + off,
                  (char*)Bs + (wv << 10));
      const int c2 = tid + 256;
      const int row2 = c2 >> 2, off2 = (c2 & 3) << 4;
      gload_lds16(Bb + (size_t)(col0 + row2) * 1024 + k0 * 2 + off2,
                  (char*)Bs + 4096 + (wv << 10));
    }
    __syncthreads();
    bf16x8 a[2], b[4];
#pragma unroll
    for (int m = 0; m < 2; ++m)
      a[m] = *(const bf16x8*)(As + (wm * 32 + m * 16 + r16) * 32 + g * 8);
#pragma unroll
    for (int n = 0; n < 4; ++n)
      b[n] = *(const bf16x8*)(Bs + (wn * 64 + n * 16 + r16) * 32 + g * 8);
#pragma unroll
    for (int m = 0; m < 2; ++m)
#pragma unroll
      for (int n = 0; n < 4; ++n)
        acc[m][n] = __builtin_amdgcn_mfma_f32_16x16x32_bf16(a[m], b[n], acc[m][n], 0, 0, 0);
    __syncthreads();
  }
}

// Fused Q/K/V projection: blockIdx.z selects weight slot / bias / output.
__global__ __launch_bounds__(256, 2)
void gemm_qkv_kernel(const __hip_bfloat16* __restrict__ A,
                     const __hip_bfloat16* __restrict__ WT_base, size_t wt_stride,
                     const float* __restrict__ b0, const float* __restrict__ b1,
                     const float* __restrict__ b2,
                     __hip_bfloat16* __restrict__ out_base) {
  __shared__ __attribute__((aligned(16))) __hip_bfloat16 As[2048];
  __shared__ __attribute__((aligned(16))) __hip_bfloat16 Bs[4096];
  const int z = blockIdx.z;
  const __hip_bfloat16* WT = WT_base + (size_t)z * wt_stride;
  const float* bias = (z == 0) ? b0 : (z == 1) ? b1 : b2;
  __hip_bfloat16* C = out_base + (size_t)z * (size_t)(8192 * 512);
  const int row0 = blockIdx.y * 64, col0 = blockIdx.x * 128;
  f32x4 acc[2][4];
#pragma unroll
  for (int m = 0; m < 2; ++m)
#pragma unroll
    for (int n = 0; n < 4; ++n) acc[m][n] = (f32x4)(0.0f);
  gemm_core_512(A, WT, As, Bs, row0, col0, acc);
  const int lane = threadIdx.x & 63, wv = threadIdx.x >> 6;
  const int g = lane >> 4, r16 = lane & 15, wm = wv >> 1, wn = wv & 1;
#pragma unroll
  for (int n = 0; n < 4; ++n) {
    const int col = col0 + wn * 64 + n * 16 + r16;
    const float bn = bias[col];
#pragma unroll
    for (int m = 0; m < 2; ++m) {
      const int rowb = row0 + wm * 32 + m * 16 + g * 4;
#pragma unroll
      for (int r = 0; r < 4; ++r)
        C[(size_t)(rowb + r) * 512 + col] = __float2bfloat16(acc[m][n][r] + bn);
    }
  }
}

// Fused-weight GEMM: WfT[z] = (wo_z @ outw_z)^T, batched over z (bf16 out).
__global__ __launch_bounds__(256, 2)
void gemm_fusew_kernel(const __hip_bfloat16* __restrict__ A_base,
                       const __hip_bfloat16* __restrict__ BT_base,
                       __hip_bfloat16* __restrict__ C_base) {
  __shared__ __attribute__((aligned(16))) __hip_bfloat16 As[2048];
  __shared__ __attribute__((aligned(16))) __hip_bfloat16 Bs[4096];
  const size_t MS = (size_t)512 * 512;
  const int z = blockIdx.z;
  const __hip_bfloat16* A = A_base + z * MS;
  const __hip_bfloat16* BT = BT_base + z * MS;
  __hip_bfloat16* C = C_base + z * MS;
  const int row0 = blockIdx.y * 64, col0 = blockIdx.x * 128;
  f32x4 acc[2][4];
#pragma unroll
  for (int m = 0; m < 2; ++m)
#pragma unroll
    for (int n = 0; n < 4; ++n) acc[m][n] = (f32x4)(0.0f);
  gemm_core_512(A, BT, As, Bs, row0, col0, acc);
  const int lane = threadIdx.x & 63, wv = threadIdx.x >> 6;
  const int g = lane >> 4, r16 = lane & 15, wm = wv >> 1, wn = wv & 1;
#pragma unroll
  for (int n = 0; n < 4; ++n) {
    const int col = col0 + wn * 64 + n * 16 + r16;
#pragma unroll
    for (int m = 0; m < 2; ++m) {
      const int rowb = row0 + wm * 32 + m * 16 + g * 4;
#pragma unroll
      for (int r = 0; r < 4; ++r)
        C[(size_t)(rowb + r) * 512 + col] = __float2bfloat16(acc[m][n][r]);
    }
  }
}

// Final fused output GEMM: out = sum_z abar_z @ Wf_z + sum_z bfused_z.
__global__ __launch_bounds__(256, 2)
void gemm_out_fused_kernel(const __hip_bfloat16* __restrict__ A0,
                           const __hip_bfloat16* __restrict__ A1,
                           const __hip_bfloat16* __restrict__ A2,
                           const __hip_bfloat16* __restrict__ A3,
                           const __hip_bfloat16* __restrict__ WT_base,
                           const float* __restrict__ bfused,
                           float* __restrict__ out) {
  __shared__ __attribute__((aligned(16))) __hip_bfloat16 As[2048];
  __shared__ __attribute__((aligned(16))) __hip_bfloat16 Bs[4096];
  const size_t MS = (size_t)512 * 512;
  const int row0 = blockIdx.y * 64, col0 = blockIdx.x * 128;
  f32x4 acc[2][4];
#pragma unroll
  for (int m = 0; m < 2; ++m)
#pragma unroll
    for (int n = 0; n < 4; ++n) acc[m][n] = (f32x4)(0.0f);
  const __hip_bfloat16* Az[4] = {A0, A1, A2, A3};
  for (int z = 0; z < 4; ++z)
    gemm_core_512(Az[z], WT_base + (size_t)z * MS, As, Bs, row0, col0, acc);
  const int lane = threadIdx.x & 63, wv = threadIdx.x >> 6;
  const int g = lane >> 4, r16 = lane & 15, wm = wv >> 1, wn = wv & 1;
#pragma unroll
  for (int n = 0; n < 4; ++n) {
    const int col = col0 + wn * 64 + n * 16 + r16;
    const float bn = bfused[col] + bfused[512 + col] + bfused[1024 + col] +
                     bfused[1536 + col];
#pragma unroll
    for (int m = 0; m < 2; ++m) {
      const int rowb = row0 + wm * 32 + m * 16 + g * 4;
#pragma unroll
      for (int r = 0; r < 4; ++r)
        out[(size_t)(rowb + r) * 512 + col] = acc[m][n][r] + bn;
    }
  }
}

// =====================================================================
// Local windowed attention v5: lane-local everything.
// Lane = (h, pq): h = lane>>3, pq = lane&7, active iff pq < W.
// Each active lane owns att row m = h*W+pq entirely: full 64-d dots,
// lane-local softmax (ZERO cross-lane ops in chains), in-lane PV over
// two 32-feature halves (register cap). K/V/q rows read from global/L2
// (7 pq-lanes per head share addresses -> coalescer dedupes).
// j-mean: one LDS scratch round-trip per t, stride 33 dwords
// (bank=(m+d)&31 -> <=2-way, free), single __syncthreads.
// =====================================================================
template <int W>
__global__ __launch_bounds__(256, 4)
void local_attn_kernel(const __hip_bfloat16* __restrict__ Xq,
                       const __hip_bfloat16* __restrict__ Xk,
                       const __hip_bfloat16* __restrict__ Xv,
                       const float* __restrict__ bq, const float* __restrict__ bk,
                       const float* __restrict__ bv,
                       __hip_bfloat16* __restrict__ abar) {
  constexpr int PAD = (W - 1) / 2;
  __shared__ unsigned scr[4][8 * W][33];
  const int tid = threadIdx.x;
  const int wv = tid >> 6, lane = tid & 63;
  const int bt = (blockIdx.x << 2) + wv;
  const int b = bt >> 10, t = bt & 1023;
  const int h = lane >> 3, pq = lane & 7;

  if (pq < W) {
    const int mq = h * W + pq;
    const int jq = mq >> 3, cq = mq & 7;
    const int sq = t + jq - PAD;

    // q row: 64 bf16 in 8 u16x8
    u16x8 q8[8];
    if (sq >= 0 && sq < T_SEQ) {
      const __hip_bfloat16* qp = Xq + ((size_t)(b * T_SEQ + sq) << 9) + cq * 64;
#pragma unroll
      for (int e = 0; e < 8; ++e) q8[e] = *(const u16x8*)(qp + e * 8);
    } else {
      const float* bp = bq + cq * 64;
#pragma unroll
      for (int e = 0; e < 8; ++e)
#pragma unroll
        for (int u = 0; u < 8; ++u) q8[e][u] = f2bf(bp[e * 8 + u]);
    }

    // ---- scores: full 64-d dot per pk, all in-lane ----
    float p_[W];
#pragma unroll
    for (int pk = 0; pk < W; ++pk) {
      const int mk = h * W + pk;
      const int jk = mk >> 3, ck = mk & 7;
      const int sk = t + jk - PAD;
      u16x8 kv8[8];
      if (sk >= 0 && sk < T_SEQ) {
        const __hip_bfloat16* kp = Xk + ((size_t)(b * T_SEQ + sk) << 9) + ck * 64;
#pragma unroll
        for (int e = 0; e < 8; ++e) kv8[e] = *(const u16x8*)(kp + e * 8);
      } else {
        const float* bp = bk + ck * 64;
#pragma unroll
        for (int e = 0; e < 8; ++e)
#pragma unroll
          for (int u = 0; u < 8; ++u) kv8[e][u] = f2bf(bp[e * 8 + u]);
      }
      float d0 = 0.f, d1 = 0.f, d2 = 0.f, d3 = 0.f;
#pragma unroll
      for (int e = 0; e < 8; ++e) {
        d0 = fmaf(bf2f(q8[e][0]), bf2f(kv8[e][0]), d0);
        d1 = fmaf(bf2f(q8[e][1]), bf2f(kv8[e][1]), d1);
        d2 = fmaf(bf2f(q8[e][2]), bf2f(kv8[e][2]), d2);
        d3 = fmaf(bf2f(q8[e][3]), bf2f(kv8[e][3]), d3);
        d0 = fmaf(bf2f(q8[e][4]), bf2f(kv8[e][4]), d0);
        d1 = fmaf(bf2f(q8[e][5]), bf2f(kv8[e][5]), d1);
        d2 = fmaf(bf2f(q8[e][6]), bf2f(kv8[e][6]), d2);
        d3 = fmaf(bf2f(q8[e][7]), bf2f(kv8[e][7]), d3);
      }
      p_[pk] = ((d0 + d1) + (d2 + d3)) * 0.125f;
    }

    // ---- lane-local softmax over pk ----
    float mx = p_[0];
#pragma unroll
    for (int pk = 1; pk < W; ++pk) mx = fmaxf(mx, p_[pk]);
    float sum = 0.f;
#pragma unroll
    for (int pk = 0; pk < W; ++pk) {
      p_[pk] = __expf(p_[pk] - mx);
      sum += p_[pk];
    }
    const float inv = 1.f / sum;
#pragma unroll
    for (int pk = 0; pk < W; ++pk) p_[pk] *= inv;

    // ---- PV in two 32-feature halves (register cap), pack to bf16 ----
    unsigned packed[32];
#pragma unroll
    for (int half = 0; half < 2; ++half) {
      float av[32];
#pragma unroll
      for (int e = 0; e < 32; ++e) av[e] = 0.f;
#pragma unroll
      for (int pk = 0; pk < W; ++pk) {
        const int mk = h * W + pk;
        const int jk = mk >> 3, ck = mk & 7;
        const int sk = t + jk - PAD;
        u16x8 vv[4];
        if (sk >= 0 && sk < T_SEQ) {
          const __hip_bfloat16* vp =
              Xv + ((size_t)(b * T_SEQ + sk) << 9) + ck * 64 + half * 32;
#pragma unroll
          for (int e = 0; e < 4; ++e) vv[e] = *(const u16x8*)(vp + e * 8);
        } else {
          const float* bp = bv + ck * 64 + half * 32;
#pragma unroll
          for (int e = 0; e < 4; ++e)
#pragma unroll
            for (int u = 0; u < 8; ++u) vv[e][u] = f2bf(bp[e * 8 + u]);
        }
        const float p = p_[pk];
#pragma unroll
        for (int e = 0; e < 4; ++e)
#pragma unroll
          for (int u = 0; u < 8; ++u)
            av[e * 8 + u] = fmaf(p, bf2f(vv[e][u]), av[e * 8 + u]);
      }
#pragma unroll
      for (int d = 0; d < 16; ++d)
        CVTPK(packed[half * 16 + d], av[2 * d], av[2 * d + 1]);
    }

    // ---- write att row m to scratch (stride 33 -> <=2-way banks) ----
    unsigned* row = &scr[wv][mq][0];
#pragma unroll
    for (int d = 0; d < 32; ++d) row[d] = packed[d];
  }

  __syncthreads();

  // ---- j-mean: out lane (c, fb) sums rows m = j*8+c, feats fb*8.. ----
  const int c = lane >> 3, fb = lane & 7;
  float o[8] = {0.f, 0.f, 0.f, 0.f, 0.f, 0.f, 0.f, 0.f};
#pragma unroll
  for (int j = 0; j < W; ++j) {
    const unsigned* row = &scr[wv][j * 8 + c][fb * 4];
#pragma unroll
    for (int k = 0; k < 4; ++k) {
      const unsigned dw = row[k];
      o[2 * k]     += bf2f((unsigned short)(dw & 0xffff));
      o[2 * k + 1] += bf2f((unsigned short)(dw >> 16));
    }
  }
  const float invw = 1.f / (float)W;
  u16x8 ov;
#pragma unroll
  for (int e = 0; e < 8; ++e) ov[e] = f2bf(o[e] * invw);
  *(u16x8*)(abar + ((size_t)bt << 9) + c * 64 + fb * 8) = ov;
}

// =====================================================================
// Global attention, MFMA flash (32x32x16 bf16, swapped operands).
// (unchanged — already fast)
// =====================================================================
__global__ __launch_bounds__(256)
void global_attn_mfma_kernel(const __hip_bfloat16* __restrict__ Xq,
                             const __hip_bfloat16* __restrict__ Xk,
                             const __hip_bfloat16* __restrict__ Xv,
                             __hip_bfloat16* __restrict__ att) {
  __shared__ unsigned vt[2][2048];
  const int tid = threadIdx.x;
  const int lane = tid & 63;
  const int wv = tid >> 6;
  const int qblk = blockIdx.x;
  const int bh = blockIdx.y;
  const size_t base = (size_t)bh << 16;
  const int c = lane & 31;
  const int g = lane >> 5;
  const int q0 = qblk * 128 + wv * 32;

  const __hip_bfloat16* Qp = Xq + base;
  const __hip_bfloat16* Kp = Xk + base;
  const __hip_bfloat16* Vp = Xv + base;

  bf16x8 qf[4];
#pragma unroll
  for (int s = 0; s < 4; ++s)
    qf[s] = *(const bf16x8*)(Qp + (size_t)(q0 + c) * 64 + s * 16 + g * 8);

  const int k2 = tid & 31, dblk = tid >> 5;

  bf16x8 kf[2][4];
  u16x8 v0, v1, v0n, v1n;

  v0 = *(const u16x8*)(Vp + (size_t)(2 * k2) * 64 + dblk * 8);
  v1 = *(const u16x8*)(Vp + (size_t)(2 * k2 + 1) * 64 + dblk * 8);
#pragma unroll
  for (int kb = 0; kb < 2; ++kb)
#pragma unroll
    for (int s = 0; s < 4; ++s)
      kf[kb][s] = *(const bf16x8*)(Kp + (size_t)(kb * 32 + c) * 64 + s * 16 + g * 8);

  f32x16 Oa = (f32x16)(0.0f), Ob = (f32x16)(0.0f);
  float m_run = -3e38f, l_run = 0.f;

  for (int kt = 0; kt < 16; ++kt) {
    unsigned* vb = &vt[kt & 1][0];
#pragma unroll
    for (int jj = 0; jj < 8; ++jj) {
      const int d = dblk * 8 + jj;
      const unsigned dw = (unsigned)v0[jj] | ((unsigned)v1[jj] << 16);
      const int byte = (d * 128 + k2 * 4) ^ ((d & 7) << 4);
      vb[byte >> 2] = dw;
    }
    if (kt < 15) {
      const __hip_bfloat16* vsrc = Vp + (size_t)((kt + 1) * 64 + 2 * k2) * 64 + dblk * 8;
      v0n = *(const u16x8*)vsrc;
      v1n = *(const u16x8*)(vsrc + 64);
    }
    __syncthreads();

    f32x16 sa = (f32x16)(0.0f), sb = (f32x16)(0.0f);
#pragma unroll
    for (int s = 0; s < 4; ++s)
      sa = __builtin_amdgcn_mfma_f32_32x32x16_bf16(kf[0][s], qf[s], sa, 0, 0, 0);
#pragma unroll
    for (int s = 0; s < 4; ++s)
      sb = __builtin_amdgcn_mfma_f32_32x32x16_bf16(kf[1][s], qf[s], sb, 0, 0, 0);

    if (kt < 15) {
#pragma unroll
      for (int kb = 0; kb < 2; ++kb)
#pragma unroll
        for (int s = 0; s < 4; ++s)
          kf[kb][s] = *(const bf16x8*)(Kp + (size_t)((kt + 1) * 64 + kb * 32 + c) * 64 +
                                       s * 16 + g * 8);
    }

    float mx = sa[0];
#pragma unroll
    for (int r = 1; r < 16; ++r) mx = fmaxf(mx, sa[r]);
#pragma unroll
    for (int r = 0; r < 16; ++r) mx = fmaxf(mx, sb[r]);
    mx = fmaxf(mx, __shfl_xor(mx, 32));
    const float m_new = fmaxf(m_run, mx * 0.125f);
    const float alpha = __expf(m_run - m_new);

    float p0[16], p1[16];
    float lsum = 0.f;
#pragma unroll
    for (int r = 0; r < 16; ++r) { p0[r] = __expf(fmaf(sa[r], 0.125f, -m_new)); lsum += p0[r]; }
#pragma unroll
    for (int r = 0; r < 16; ++r) { p1[r] = __expf(fmaf(sb[r], 0.125f, -m_new)); lsum += p1[r]; }
    lsum += __shfl_xor(lsum, 32);
    l_run = fmaf(l_run, alpha, lsum);
    m_run = m_new;
#pragma unroll
    for (int r = 0; r < 16; ++r) { Oa[r] *= alpha; Ob[r] *= alpha; }

    unsigned bw[2][2][4];
#define REDIST(pb, kb_)                                                  \
    {                                                                    \
      unsigned t0_, t1_, t2_, t3_, t4_, t5_, t6_, t7_;                   \
      CVTPK(t0_, pb[0], pb[1]);   CVTPK(t1_, pb[2], pb[3]);              \
      CVTPK(t2_, pb[4], pb[5]);   CVTPK(t3_, pb[6], pb[7]);              \
      CVTPK(t4_, pb[8], pb[9]);   CVTPK(t5_, pb[10], pb[11]);            \
      CVTPK(t6_, pb[12], pb[13]); CVTPK(t7_, pb[14], pb[15]);            \
      swap32(t0_, t2_, lane); swap32(t1_, t3_, lane);                    \
      swap32(t4_, t6_, lane); swap32(t5_, t7_, lane);                    \
      bw[kb_][0][0] = t0_; bw[kb_][0][1] = t1_; bw[kb_][0][2] = t2_;     \
      bw[kb_][0][3] = t3_;                                               \
      bw[kb_][1][0] = t4_; bw[kb_][1][1] = t5_; bw[kb_][1][2] = t6_;     \
      bw[kb_][1][3] = t7_;                                               \
    }
    REDIST(p0, 0)
    REDIST(p1, 1)
#undef REDIST

    const unsigned* vbr = &vt[kt & 1][0];
#pragma unroll
    for (int kb = 0; kb < 2; ++kb)
#pragma unroll
      for (int st = 0; st < 2; ++st) {
        const u32x4 pw = { bw[kb][st][0], bw[kb][st][1], bw[kb][st][2], bw[kb][st][3] };
        const bf16x8 pf = __builtin_bit_cast(bf16x8, pw);
        {
          const int row = c;
          const int off = (row * 128 + (kb * 64 + st * 32 + g * 16)) ^ ((row & 7) << 4);
          const bf16x8 va = __builtin_bit_cast(bf16x8, *(const u32x4*)((const char*)vbr + off));
          Oa = __builtin_amdgcn_mfma_f32_32x32x16_bf16(va, pf, Oa, 0, 0, 0);
        }
        {
          const int row = 32 + c;
          const int off = (row * 128 + (kb * 64 + st * 32 + g * 16)) ^ ((row & 7) << 4);
          const bf16x8 va = __builtin_bit_cast(bf16x8, *(const u32x4*)((const char*)vbr + off));
          Ob = __builtin_amdgcn_mfma_f32_32x32x16_bf16(va, pf, Ob, 0, 0, 0);
        }
      }

    v0 = v0n; v1 = v1n;
  }

  const float inv = 1.f / l_run;
  __hip_bfloat16* drow = att + base + (size_t)(q0 + c) * 64;
#pragma unroll
  for (int qd = 0; qd < 4; ++qd) {
    unsigned lo, hi;
    {
      const float a0 = Oa[4 * qd + 0] * inv, a1 = Oa[4 * qd + 1] * inv;
      const float a2 = Oa[4 * qd + 2] * inv, a3 = Oa[4 * qd + 3] * inv;
      CVTPK(lo, a0, a1); CVTPK(hi, a2, a3);
      uint2 w; w.x = lo; w.y = hi;
      *(uint2*)(drow + 8 * qd + 4 * g) = w;
    }
    {
      const float a0 = Ob[4 * qd + 0] * inv, a1 = Ob[4 * qd + 1] * inv;
      const float a2 = Ob[4 * qd + 2] * inv, a3 = Ob[4 * qd + 3] * inv;
      CVTPK(lo, a0, a1); CVTPK(hi, a2, a3);
      uint2 w; w.x = lo; w.y = hi;
      *(uint2*)(drow + 32 + 8 * qd + 4 * g) = w;
    }
  }
}

// =====================================================================
// Launch
// =====================================================================
extern "C" void kernel_launch(void* const* d_in, const int* in_sizes, int n_in,
                              void* d_out, int out_size, void* d_ws, size_t ws_size,
                              hipStream_t stream) {
  const float* x      = (const float*)d_in[0];
  const float* loc_wq = (const float*)d_in[1];
  const float* loc_bq = (const float*)d_in[2];
  const float* loc_wk = (const float*)d_in[3];
  const float* loc_bk = (const float*)d_in[4];
  const float* loc_wv = (const float*)d_in[5];
  const float* loc_bv = (const float*)d_in[6];
  const float* loc_wo = (const float*)d_in[7];
  const float* loc_bo = (const float*)d_in[8];
  const float* g_wq  = (const float*)d_in[9];
  const float* g_bq  = (const float*)d_in[10];
  const float* g_wk  = (const float*)d_in[11];
  const float* g_bk  = (const float*)d_in[12];
  const float* g_wv  = (const float*)d_in[13];
  const float* g_bv  = (const float*)d_in[14];
  const float* g_wo  = (const float*)d_in[15];
  const float* g_bo  = (const float*)d_in[16];
  const float* out_w = (const float*)d_in[17];
  const float* out_b = (const float*)d_in[18];
  float* out = (float*)d_out;

  __hip_bfloat16* wsb = (__hip_bfloat16*)d_ws;
  const size_t SZ = (size_t)8192 * 512;
  const size_t MS = (size_t)512 * 512;
  // WT slots: 0-8 loc qkv, 9-11 g qkv, 12-15 outw^T, 16-18 loc_wo (plain),
  //           19 g_wo (plain), 20-23 Wfused^T
  __hip_bfloat16* xb    = wsb;
  __hip_bfloat16* WT    = wsb + SZ;
  __hip_bfloat16* Xq    = wsb + SZ + 24 * MS;
  __hip_bfloat16* Xk    = Xq + SZ;
  __hip_bfloat16* Xv    = Xq + 2 * SZ;
  __hip_bfloat16* abar0 = Xq + 3 * SZ;
  __hip_bfloat16* abar1 = Xq + 4 * SZ;
  __hip_bfloat16* abar2 = Xq + 5 * SZ;
  __hip_bfloat16* abar3 = Xq + 6 * SZ;
  float* bfused = (float*)(Xq + 7 * SZ);   // 4 x 512 fp32
  __hip_bfloat16* abars[3] = {abar0, abar1, abar2};

  const dim3 thr(256);

  // ---- one-time prep (2 dispatches + 2 small fusions) ----
  cast_x_kernel<<<2048, thr, 0, stream>>>(x, xb);
  prep_weights_kernel<<<dim3(256, 20), thr, 0, stream>>>(
      loc_wq, loc_wk, loc_wv, g_wq, g_wk, g_wv, out_w, loc_wo, g_wo, WT);
  gemm_fusew_kernel<<<dim3(4, 8, 4), thr, 0, stream>>>(WT + 12 * MS, WT + 16 * MS,
                                                       WT + 20 * MS);
  bias_fuse_kernel<<<dim3(2, 4), thr, 0, stream>>>(loc_bo, g_bo, out_w, out_b, bfused);

  const dim3 ggrid(4, 128);
  const dim3 gqkv(4, 128, 3);

  for (int lv = 0; lv < 3; ++lv) {
    gemm_qkv_kernel<<<gqkv, thr, 0, stream>>>(
        xb, WT + lv * MS, 3 * MS,
        loc_bq + lv * 512, loc_bk + lv * 512, loc_bv + lv * 512, Xq);

    if (lv == 0)
      local_attn_kernel<3><<<2048, thr, 0, stream>>>(
          Xq, Xk, Xv, loc_bq + lv * 512, loc_bk + lv * 512, loc_bv + lv * 512, abars[lv]);
    else if (lv == 1)
      local_attn_kernel<5><<<2048, thr, 0, stream>>>(
          Xq, Xk, Xv, loc_bq + lv * 512, loc_bk + lv * 512, loc_bv + lv * 512, abars[lv]);
    else
      local_attn_kernel<7><<<2048, thr, 0, stream>>>(
          Xq, Xk, Xv, loc_bq + lv * 512, loc_bk + lv * 512, loc_bv + lv * 512, abars[lv]);
  }

  // global branch
  gemm_qkv_kernel<<<gqkv, thr, 0, stream>>>(xb, WT + 9 * MS, MS, g_bq, g_bk, g_bv, Xq);
  global_attn_mfma_kernel<<<dim3(8, 64), thr, 0, stream>>>(Xq, Xk, Xv, abar3);

  // fused output projection: one K=2048 GEMM, out written once
  gemm_out_fused_kernel<<<ggrid, thr, 0, stream>>>(abar0, abar1, abar2, abar3,
                                                   WT + 20 * MS, bfused, out);
}

// Round 7
// 305.704 us; speedup vs baseline: 4.0914x; 4.0914x over previous
//
#include <hip/hip_runtime.h>
#include <hip/hip_bf16.h>
#include <cstddef>

#define T_SEQ 1024
#define D_MODEL 512

typedef __attribute__((ext_vector_type(8))) __bf16 bf16x8;
typedef __attribute__((ext_vector_type(4))) float f32x4;
typedef __attribute__((ext_vector_type(16))) float f32x16;
typedef __attribute__((ext_vector_type(8))) unsigned short u16x8;
typedef __attribute__((ext_vector_type(4))) unsigned int u32x4;

typedef const unsigned int __attribute__((address_space(1)))* gas1_t;
typedef unsigned int __attribute__((address_space(3)))* las3_t;

__device__ __forceinline__ void gload_lds16(const void* g, void* l) {
  __builtin_amdgcn_global_load_lds((gas1_t)g, (las3_t)l, 16, 0, 0);
}

__device__ __forceinline__ float bf2f(unsigned short u) {
  return __uint_as_float(((unsigned)u) << 16);
}
__device__ __forceinline__ unsigned short f2bf(float f) {
  __hip_bfloat16 h = __float2bfloat16(f);
  return *(unsigned short*)&h;
}

#define CVTPK(dst, a, b) \
  asm("v_cvt_pk_bf16_f32 %0, %1, %2" : "=v"(dst) : "v"(a), "v"(b))

// exchange lane halves between two dwords (global attn P redistribution)
__device__ __forceinline__ void swap32(unsigned& a, unsigned& b, int lane) {
  const unsigned ax = __shfl_xor(a, 32);
  const unsigned bx = __shfl_xor(b, 32);
  const bool lo = lane < 32;
  const unsigned na = lo ? a : bx;
  const unsigned nb = lo ? ax : b;
  a = na; b = nb;
}

// =====================================================================
// Cast fp32 -> bf16 (each thread 8 elems)
// =====================================================================
__global__ __launch_bounds__(256)
void cast_x_kernel(const float* __restrict__ in, __hip_bfloat16* __restrict__ out) {
  const int i = (blockIdx.x * 256 + threadIdx.x) * 8;
  const float4 a = *(const float4*)(in + i);
  const float4 b = *(const float4*)(in + i + 4);
  u16x8 o;
  o[0] = f2bf(a.x); o[1] = f2bf(a.y); o[2] = f2bf(a.z); o[3] = f2bf(a.w);
  o[4] = f2bf(b.x); o[5] = f2bf(b.y); o[6] = f2bf(b.z); o[7] = f2bf(b.w);
  *(u16x8*)(out + i) = o;
}

// =====================================================================
// ALL weight prep in ONE dispatch. z = blockIdx.y selects matrix:
//  0-2 loc_wq (T), 3-5 loc_wk (T), 6-8 loc_wv (T), 9 g_wq, 10 g_wk,
//  11 g_wv (T), 12-15 out_w (T), 16-18 loc_wo (plain), 19 g_wo (plain).
// =====================================================================
__global__ __launch_bounds__(256)
void prep_weights_kernel(const float* __restrict__ loc_wq, const float* __restrict__ loc_wk,
                         const float* __restrict__ loc_wv, const float* __restrict__ g_wq,
                         const float* __restrict__ g_wk, const float* __restrict__ g_wv,
                         const float* __restrict__ out_w, const float* __restrict__ loc_wo,
                         const float* __restrict__ g_wo, __hip_bfloat16* __restrict__ WT) {
  __shared__ float tile[32][33];
  const size_t MS = (size_t)512 * 512;
  const int z = blockIdx.y;
  const float* src;
  bool tr = true;
  if (z < 3)       src = loc_wq + (size_t)z * MS;
  else if (z < 6)  src = loc_wk + (size_t)(z - 3) * MS;
  else if (z < 9)  src = loc_wv + (size_t)(z - 6) * MS;
  else if (z == 9)  src = g_wq;
  else if (z == 10) src = g_wk;
  else if (z == 11) src = g_wv;
  else if (z < 16) src = out_w + (size_t)(z - 12) * MS;
  else if (z < 19) { src = loc_wo + (size_t)(z - 16) * MS; tr = false; }
  else             { src = g_wo; tr = false; }
  __hip_bfloat16* dst = WT + (size_t)z * MS;

  const int tk = (blockIdx.x & 15) * 32;
  const int tn = (blockIdx.x >> 4) * 32;
  const int t = threadIdx.x;
  const int r = t >> 3, c4 = (t & 7) * 4;
  const float4 v = *(const float4*)(src + (size_t)(tk + r) * 512 + tn + c4);
  if (tr) {
    tile[r][c4 + 0] = v.x; tile[r][c4 + 1] = v.y;
    tile[r][c4 + 2] = v.z; tile[r][c4 + 3] = v.w;
    __syncthreads();
    ushort4 o;
    o.x = f2bf(tile[c4 + 0][r]); o.y = f2bf(tile[c4 + 1][r]);
    o.z = f2bf(tile[c4 + 2][r]); o.w = f2bf(tile[c4 + 3][r]);
    *(ushort4*)(dst + (size_t)(tn + r) * 512 + tk + c4) = o;
  } else {
    ushort4 o;
    o.x = f2bf(v.x); o.y = f2bf(v.y); o.z = f2bf(v.z); o.w = f2bf(v.w);
    *(ushort4*)(dst + (size_t)(tk + r) * 512 + tn + c4) = o;
  }
}

// cast local q/k/v biases to bf16: dst[(lv*3+role)*512 + e]
__global__ __launch_bounds__(256)
void cast_biases_kernel(const float* __restrict__ loc_bq, const float* __restrict__ loc_bk,
                        const float* __restrict__ loc_bv, __hip_bfloat16* __restrict__ dst) {
  const int i = blockIdx.x * 256 + threadIdx.x;
  if (i < 9 * 512) {
    const int which = i >> 9, lv = which / 3, role = which % 3, e = i & 511;
    const float* src = role == 0 ? loc_bq : role == 1 ? loc_bk : loc_bv;
    dst[i] = __float2bfloat16(src[lv * 512 + e]);
  }
}

// =====================================================================
// Fused bias: bfused[z][n] = bo_z @ out_w[z*512..] (+ out_b for z==0).
// =====================================================================
__global__ __launch_bounds__(256)
void bias_fuse_kernel(const float* __restrict__ loc_bo, const float* __restrict__ g_bo,
                      const float* __restrict__ out_w, const float* __restrict__ out_b,
                      float* __restrict__ bfused) {
  const int z = blockIdx.y;
  const int n = blockIdx.x * 256 + threadIdx.x;
  const float* bo = (z < 3) ? loc_bo + z * 512 : g_bo;
  const float* W = out_w + (size_t)z * 512 * 512;
  float acc = (z == 0) ? out_b[n] : 0.f;
  for (int m = 0; m < 512; ++m)
    acc = fmaf(bo[m], W[(size_t)m * 512 + n], acc);
  bfused[z * 512 + n] = acc;
}

// =====================================================================
// MFMA GEMM core: BM=64 BN=128 BK=32. ACCUMULATES into acc.
// =====================================================================
__device__ __forceinline__ void gemm_core_512(
    const __hip_bfloat16* __restrict__ A, const __hip_bfloat16* __restrict__ BT,
    __hip_bfloat16* As, __hip_bfloat16* Bs, int row0, int col0, f32x4 acc[2][4]) {
  const int tid = threadIdx.x;
  const int wv = tid >> 6, lane = tid & 63;
  const int g = lane >> 4, r16 = lane & 15;
  const int wm = wv >> 1, wn = wv & 1;
  const char* Ab = (const char*)A;
  const char* Bb = (const char*)BT;
  for (int k0 = 0; k0 < 512; k0 += 32) {
    {
      const int row = tid >> 2, off = (tid & 3) << 4;
      gload_lds16(Ab + (size_t)(row0 + row) * 1024 + k0 * 2 + off,
                  (char*)As + (wv << 10));
    }
    {
      const int row = tid >> 2, off = (tid & 3) << 4;
      gload_lds16(Bb + (size_t)(col0 + row) * 1024 + k0 * 2 + off,
                  (char*)Bs + (wv << 10));
      const int c2 = tid + 256;
      const int row2 = c2 >> 2, off2 = (c2 & 3) << 4;
      gload_lds16(Bb + (size_t)(col0 + row2) * 1024 + k0 * 2 + off2,
                  (char*)Bs + 4096 + (wv << 10));
    }
    __syncthreads();
    bf16x8 a[2], b[4];
#pragma unroll
    for (int m = 0; m < 2; ++m)
      a[m] = *(const bf16x8*)(As + (wm * 32 + m * 16 + r16) * 32 + g * 8);
#pragma unroll
    for (int n = 0; n < 4; ++n)
      b[n] = *(const bf16x8*)(Bs + (wn * 64 + n * 16 + r16) * 32 + g * 8);
#pragma unroll
    for (int m = 0; m < 2; ++m)
#pragma unroll
      for (int n = 0; n < 4; ++n)
        acc[m][n] = __builtin_amdgcn_mfma_f32_16x16x32_bf16(a[m], b[n], acc[m][n], 0, 0, 0);
    __syncthreads();
  }
}

__global__ __launch_bounds__(256, 2)
void gemm_qkv_kernel(const __hip_bfloat16* __restrict__ A,
                     const __hip_bfloat16* __restrict__ WT_base, size_t wt_stride,
                     const float* __restrict__ b0, const float* __restrict__ b1,
                     const float* __restrict__ b2,
                     __hip_bfloat16* __restrict__ out_base) {
  __shared__ __attribute__((aligned(16))) __hip_bfloat16 As[2048];
  __shared__ __attribute__((aligned(16))) __hip_bfloat16 Bs[4096];
  const int z = blockIdx.z;
  const __hip_bfloat16* WT = WT_base + (size_t)z * wt_stride;
  const float* bias = (z == 0) ? b0 : (z == 1) ? b1 : b2;
  __hip_bfloat16* C = out_base + (size_t)z * (size_t)(8192 * 512);
  const int row0 = blockIdx.y * 64, col0 = blockIdx.x * 128;
  f32x4 acc[2][4];
#pragma unroll
  for (int m = 0; m < 2; ++m)
#pragma unroll
    for (int n = 0; n < 4; ++n) acc[m][n] = (f32x4)(0.0f);
  gemm_core_512(A, WT, As, Bs, row0, col0, acc);
  const int lane = threadIdx.x & 63, wv = threadIdx.x >> 6;
  const int g = lane >> 4, r16 = lane & 15, wm = wv >> 1, wn = wv & 1;
#pragma unroll
  for (int n = 0; n < 4; ++n) {
    const int col = col0 + wn * 64 + n * 16 + r16;
    const float bn = bias[col];
#pragma unroll
    for (int m = 0; m < 2; ++m) {
      const int rowb = row0 + wm * 32 + m * 16 + g * 4;
#pragma unroll
      for (int r = 0; r < 4; ++r)
        C[(size_t)(rowb + r) * 512 + col] = __float2bfloat16(acc[m][n][r] + bn);
    }
  }
}

__global__ __launch_bounds__(256, 2)
void gemm_fusew_kernel(const __hip_bfloat16* __restrict__ A_base,
                       const __hip_bfloat16* __restrict__ BT_base,
                       __hip_bfloat16* __restrict__ C_base) {
  __shared__ __attribute__((aligned(16))) __hip_bfloat16 As[2048];
  __shared__ __attribute__((aligned(16))) __hip_bfloat16 Bs[4096];
  const size_t MS = (size_t)512 * 512;
  const int z = blockIdx.z;
  const __hip_bfloat16* A = A_base + z * MS;
  const __hip_bfloat16* BT = BT_base + z * MS;
  __hip_bfloat16* C = C_base + z * MS;
  const int row0 = blockIdx.y * 64, col0 = blockIdx.x * 128;
  f32x4 acc[2][4];
#pragma unroll
  for (int m = 0; m < 2; ++m)
#pragma unroll
    for (int n = 0; n < 4; ++n) acc[m][n] = (f32x4)(0.0f);
  gemm_core_512(A, BT, As, Bs, row0, col0, acc);
  const int lane = threadIdx.x & 63, wv = threadIdx.x >> 6;
  const int g = lane >> 4, r16 = lane & 15, wm = wv >> 1, wn = wv & 1;
#pragma unroll
  for (int n = 0; n < 4; ++n) {
    const int col = col0 + wn * 64 + n * 16 + r16;
#pragma unroll
    for (int m = 0; m < 2; ++m) {
      const int rowb = row0 + wm * 32 + m * 16 + g * 4;
#pragma unroll
      for (int r = 0; r < 4; ++r)
        C[(size_t)(rowb + r) * 512 + col] = __float2bfloat16(acc[m][n][r]);
    }
  }
}

__global__ __launch_bounds__(256, 2)
void gemm_out_fused_kernel(const __hip_bfloat16* __restrict__ A0,
                           const __hip_bfloat16* __restrict__ A1,
                           const __hip_bfloat16* __restrict__ A2,
                           const __hip_bfloat16* __restrict__ A3,
                           const __hip_bfloat16* __restrict__ WT_base,
                           const float* __restrict__ bfused,
                           float* __restrict__ out) {
  __shared__ __attribute__((aligned(16))) __hip_bfloat16 As[2048];
  __shared__ __attribute__((aligned(16))) __hip_bfloat16 Bs[4096];
  const size_t MS = (size_t)512 * 512;
  const int row0 = blockIdx.y * 64, col0 = blockIdx.x * 128;
  f32x4 acc[2][4];
#pragma unroll
  for (int m = 0; m < 2; ++m)
#pragma unroll
    for (int n = 0; n < 4; ++n) acc[m][n] = (f32x4)(0.0f);
  const __hip_bfloat16* Az[4] = {A0, A1, A2, A3};
  for (int z = 0; z < 4; ++z)
    gemm_core_512(Az[z], WT_base + (size_t)z * MS, As, Bs, row0, col0, acc);
  const int lane = threadIdx.x & 63, wv = threadIdx.x >> 6;
  const int g = lane >> 4, r16 = lane & 15, wm = wv >> 1, wn = wv & 1;
#pragma unroll
  for (int n = 0; n < 4; ++n) {
    const int col = col0 + wn * 64 + n * 16 + r16;
    const float bn = bfused[col] + bfused[512 + col] + bfused[1024 + col] +
                     bfused[1536 + col];
#pragma unroll
    for (int m = 0; m < 2; ++m) {
      const int rowb = row0 + wm * 32 + m * 16 + g * 4;
#pragma unroll
      for (int r = 0; r < 4; ++r)
        out[(size_t)(rowb + r) * 512 + col] = acc[m][n][r] + bn;
    }
  }
}

// =====================================================================
// Local windowed attention v6 — MFMA (32x32x16), one wave per (b,t).
// All 8 heads as 2 groups of 4 heads; slots = h_loc*8 + p (p<W valid).
// S^T = mfma(K,Q) block-diagonal (cross-head masked at exp);
// softmax per 8-row head-block: 1 xor32 for max + 1 for sum;
// P->B-frag: the col's own head-block is the ONLY nonzero block ->
// 2 cvtpk + 2 xor32 per group; PV: O^T = mfma(V^T, P^T) with V^T
// pair-packed + XOR-swizzled in wave-private LDS (global_attn pattern).
// No barriers. LDS region (8KB/wave) reused as j-mean scratch.
// =====================================================================
template <int W>
__device__ __forceinline__ const __hip_bfloat16* slot_row(
    const __hip_bfloat16* __restrict__ X, const __hip_bfloat16* __restrict__ biasb,
    int b, int tloc, int pg, int sl, int* ch_out) {
  constexpr int PAD = (W - 1) / 2;
  const int hloc = sl >> 3, p = sl & 7;
  const int m = (pg * 4 + hloc) * W + p;
  const int j = m >> 3;
  *ch_out = m & 7;
  int sr = tloc + j - PAD;
  if (p < W) {
    if (sr >= 0 && sr < T_SEQ) return X + ((size_t)(b * T_SEQ + sr) << 9);
    return biasb;
  }
  sr = sr < 0 ? 0 : (sr > T_SEQ - 1 ? T_SEQ - 1 : sr);
  return X + ((size_t)(b * T_SEQ + sr) << 9);
}

template <int W>
__global__ __launch_bounds__(256)
void local_attn_mfma_kernel(const __hip_bfloat16* __restrict__ Xq,
                            const __hip_bfloat16* __restrict__ Xk,
                            const __hip_bfloat16* __restrict__ Xv,
                            const __hip_bfloat16* __restrict__ bqb,
                            const __hip_bfloat16* __restrict__ bkb,
                            const __hip_bfloat16* __restrict__ bvb,
                            __hip_bfloat16* __restrict__ abar) {
  __shared__ unsigned lds_u[4][2048];
  const int tid = threadIdx.x;
  const int wv = tid >> 6, lane = tid & 63;
  const int bt = blockIdx.x * 4 + wv;
  const int b = bt >> 10, tloc = bt & 1023;
  unsigned* L = &lds_u[wv][0];
  const int dl = lane & 31, hi = lane >> 5;

  // ---- build V^T tile: lane = (pair k2=dl, dhalf=hi) ----
  {
    const int k2 = dl, dhalf = hi;
    int ch0, ch1;
    const __hip_bfloat16* r0 =
        slot_row<W>(Xv, bvb, b, tloc, (2 * k2) >> 5, (2 * k2) & 31, &ch0);
    const __hip_bfloat16* r1 =
        slot_row<W>(Xv, bvb, b, tloc, (2 * k2 + 1) >> 5, (2 * k2 + 1) & 31, &ch1);
    u16x8 A0[4], A1[4];
#pragma unroll
    for (int q = 0; q < 4; ++q) {
      A0[q] = *(const u16x8*)(r0 + ch0 * 64 + dhalf * 32 + q * 8);
      A1[q] = *(const u16x8*)(r1 + ch1 * 64 + dhalf * 32 + q * 8);
    }
#pragma unroll
    for (int q = 0; q < 4; ++q)
#pragma unroll
      for (int e = 0; e < 8; ++e) {
        const int d_ = dhalf * 32 + q * 8 + e;
        const unsigned dw = (unsigned)A0[q][e] | ((unsigned)A1[q][e] << 16);
        const int byte = (d_ * 128 + k2 * 4) ^ ((d_ & 7) << 4);
        L[byte >> 2] = dw;
      }
  }

  f32x16 accP[2][2];
#pragma unroll
  for (int pg = 0; pg < 2; ++pg)
#pragma unroll
    for (int dh = 0; dh < 2; ++dh) accP[pg][dh] = (f32x16)(0.0f);

  const int myb = dl >> 3;   // head-block of this lane's column slot

#pragma unroll
  for (int pg = 0; pg < 2; ++pg) {
    // ---- scores: S^T = mfma(K, Q), K = 64 over 4 MFMAs ----
    int chK, chQ;
    const __hip_bfloat16* rK = slot_row<W>(Xk, bkb, b, tloc, pg, dl, &chK);
    const __hip_bfloat16* rQ = slot_row<W>(Xq, bqb, b, tloc, pg, dl, &chQ);
    f32x16 sa = (f32x16)(0.0f);
#pragma unroll
    for (int i = 0; i < 4; ++i) {
      const bf16x8 kf = *(const bf16x8*)(rK + chK * 64 + i * 16 + hi * 8);
      const bf16x8 qf = *(const bf16x8*)(rQ + chQ * 64 + i * 16 + hi * 8);
      sa = __builtin_amdgcn_mfma_f32_32x32x16_bf16(kf, qf, sa, 0, 0, 0);
    }

    // ---- extract this column's head-block (constant-indexed select) ----
    float sel[4];
#pragma unroll
    for (int r4 = 0; r4 < 4; ++r4)
      sel[r4] = (myb == 0) ? sa[r4]
              : (myb == 1) ? sa[4 + r4]
              : (myb == 2) ? sa[8 + r4] : sa[12 + r4];

    // ---- softmax over the block's <=8 valid rows (1+1 shuffles) ----
    float mx = -3e38f;
#pragma unroll
    for (int r4 = 0; r4 < 4; ++r4)
      if (r4 + 4 * hi < W) mx = fmaxf(mx, sel[r4]);
    mx = fmaxf(mx, __shfl_xor(mx, 32));
    float e[4], ls = 0.f;
#pragma unroll
    for (int r4 = 0; r4 < 4; ++r4) {
      e[r4] = (r4 + 4 * hi < W) ? __expf(0.125f * (sel[r4] - mx)) : 0.f;
      ls += e[r4];
    }
    ls += __shfl_xor(ls, 32);
    const float inv = 1.f / ls;

    unsigned dw0, dw1;
    CVTPK(dw0, e[0] * inv, e[1] * inv);
    CVTPK(dw1, e[2] * inv, e[3] * inv);
    const unsigned q0 = __shfl_xor(dw0, 32);
    const unsigned q1 = __shfl_xor(dw1, 32);

    // ---- PV: O^T += V^T @ P^T ----
#pragma unroll
    for (int kh = 0; kh < 2; ++kh) {
      const bool on = (2 * kh + hi) == myb;
      u32x4 bw;
      if (hi == 0) { bw[0] = dw0; bw[1] = dw1; bw[2] = q0; bw[3] = q1; }
      else         { bw[0] = q0;  bw[1] = q1;  bw[2] = dw0; bw[3] = dw1; }
      if (!on) { bw[0] = 0u; bw[1] = 0u; bw[2] = 0u; bw[3] = 0u; }
      const bf16x8 pf = __builtin_bit_cast(bf16x8, bw);
#pragma unroll
      for (int dh = 0; dh < 2; ++dh) {
        const int d_ = dh * 32 + dl;
        const int off = (d_ * 128 + pg * 64 + kh * 32 + hi * 16) ^ ((d_ & 7) << 4);
        const bf16x8 va =
            __builtin_bit_cast(bf16x8, *(const u32x4*)((const char*)L + off));
        accP[pg][dh] = __builtin_amdgcn_mfma_f32_32x32x16_bf16(va, pf, accP[pg][dh], 0, 0, 0);
      }
    }
  }

  // ---- epilogue: scratch[m][d] (stride 34 dw), aliases vt (PV done) ----
#pragma unroll
  for (int pg = 0; pg < 2; ++pg) {
    if ((dl & 7) < W) {
      const int m_o = (pg * 4 + (dl >> 3)) * W + (dl & 7);
#pragma unroll
      for (int dh = 0; dh < 2; ++dh) {
#pragma unroll
        for (int rq = 0; rq < 4; ++rq) {
          unsigned wa, wb;
          CVTPK(wa, accP[pg][dh][4 * rq + 0], accP[pg][dh][4 * rq + 1]);
          CVTPK(wb, accP[pg][dh][4 * rq + 2], accP[pg][dh][4 * rq + 3]);
          const int dwi = m_o * 34 + dh * 16 + rq * 4 + hi * 2;
          uint2 w; w.x = wa; w.y = wb;
          *(uint2*)(L + dwi) = w;
        }
      }
    }
  }
  asm volatile("s_waitcnt lgkmcnt(0)" ::: "memory");

  // ---- j-mean: lane (ch = lane>>3, fb = lane&7) ----
  const int cho = lane >> 3, fb = lane & 7;
  float o[8] = {0.f, 0.f, 0.f, 0.f, 0.f, 0.f, 0.f, 0.f};
#pragma unroll
  for (int jj = 0; jj < W; ++jj) {
    const int mo = 8 * jj + cho;
    const uint2 w0 = *(const uint2*)(L + mo * 34 + fb * 4);
    const uint2 w1 = *(const uint2*)(L + mo * 34 + fb * 4 + 2);
    o[0] += bf2f((unsigned short)(w0.x & 0xffff));
    o[1] += bf2f((unsigned short)(w0.x >> 16));
    o[2] += bf2f((unsigned short)(w0.y & 0xffff));
    o[3] += bf2f((unsigned short)(w0.y >> 16));
    o[4] += bf2f((unsigned short)(w1.x & 0xffff));
    o[5] += bf2f((unsigned short)(w1.x >> 16));
    o[6] += bf2f((unsigned short)(w1.y & 0xffff));
    o[7] += bf2f((unsigned short)(w1.y >> 16));
  }
  const float invw = 1.f / (float)W;
  u16x8 ov;
#pragma unroll
  for (int e2 = 0; e2 < 8; ++e2) ov[e2] = f2bf(o[e2] * invw);
  *(u16x8*)(abar + ((size_t)bt << 9) + cho * 64 + fb * 8) = ov;
}

// =====================================================================
// Global attention, MFMA flash (unchanged — proven).
// =====================================================================
__global__ __launch_bounds__(256)
void global_attn_mfma_kernel(const __hip_bfloat16* __restrict__ Xq,
                             const __hip_bfloat16* __restrict__ Xk,
                             const __hip_bfloat16* __restrict__ Xv,
                             __hip_bfloat16* __restrict__ att) {
  __shared__ unsigned vt[2][2048];
  const int tid = threadIdx.x;
  const int lane = tid & 63;
  const int wv = tid >> 6;
  const int qblk = blockIdx.x;
  const int bh = blockIdx.y;
  const size_t base = (size_t)bh << 16;
  const int c = lane & 31;
  const int g = lane >> 5;
  const int q0 = qblk * 128 + wv * 32;

  const __hip_bfloat16* Qp = Xq + base;
  const __hip_bfloat16* Kp = Xk + base;
  const __hip_bfloat16* Vp = Xv + base;

  bf16x8 qf[4];
#pragma unroll
  for (int s = 0; s < 4; ++s)
    qf[s] = *(const bf16x8*)(Qp + (size_t)(q0 + c) * 64 + s * 16 + g * 8);

  const int k2 = tid & 31, dblk = tid >> 5;

  bf16x8 kf[2][4];
  u16x8 v0, v1, v0n, v1n;

  v0 = *(const u16x8*)(Vp + (size_t)(2 * k2) * 64 + dblk * 8);
  v1 = *(const u16x8*)(Vp + (size_t)(2 * k2 + 1) * 64 + dblk * 8);
#pragma unroll
  for (int kb = 0; kb < 2; ++kb)
#pragma unroll
    for (int s = 0; s < 4; ++s)
      kf[kb][s] = *(const bf16x8*)(Kp + (size_t)(kb * 32 + c) * 64 + s * 16 + g * 8);

  f32x16 Oa = (f32x16)(0.0f), Ob = (f32x16)(0.0f);
  float m_run = -3e38f, l_run = 0.f;

  for (int kt = 0; kt < 16; ++kt) {
    unsigned* vb = &vt[kt & 1][0];
#pragma unroll
    for (int jj = 0; jj < 8; ++jj) {
      const int d = dblk * 8 + jj;
      const unsigned dw = (unsigned)v0[jj] | ((unsigned)v1[jj] << 16);
      const int byte = (d * 128 + k2 * 4) ^ ((d & 7) << 4);
      vb[byte >> 2] = dw;
    }
    if (kt < 15) {
      const __hip_bfloat16* vsrc = Vp + (size_t)((kt + 1) * 64 + 2 * k2) * 64 + dblk * 8;
      v0n = *(const u16x8*)vsrc;
      v1n = *(const u16x8*)(vsrc + 64);
    }
    __syncthreads();

    f32x16 sa = (f32x16)(0.0f), sb = (f32x16)(0.0f);
#pragma unroll
    for (int s = 0; s < 4; ++s)
      sa = __builtin_amdgcn_mfma_f32_32x32x16_bf16(kf[0][s], qf[s], sa, 0, 0, 0);
#pragma unroll
    for (int s = 0; s < 4; ++s)
      sb = __builtin_amdgcn_mfma_f32_32x32x16_bf16(kf[1][s], qf[s], sb, 0, 0, 0);

    if (kt < 15) {
#pragma unroll
      for (int kb = 0; kb < 2; ++kb)
#pragma unroll
        for (int s = 0; s < 4; ++s)
          kf[kb][s] = *(const bf16x8*)(Kp + (size_t)((kt + 1) * 64 + kb * 32 + c) * 64 +
                                       s * 16 + g * 8);
    }

    float mx = sa[0];
#pragma unroll
    for (int r = 1; r < 16; ++r) mx = fmaxf(mx, sa[r]);
#pragma unroll
    for (int r = 0; r < 16; ++r) mx = fmaxf(mx, sb[r]);
    mx = fmaxf(mx, __shfl_xor(mx, 32));
    const float m_new = fmaxf(m_run, mx * 0.125f);
    const float alpha = __expf(m_run - m_new);

    float p0[16], p1[16];
    float lsum = 0.f;
#pragma unroll
    for (int r = 0; r < 16; ++r) { p0[r] = __expf(fmaf(sa[r], 0.125f, -m_new)); lsum += p0[r]; }
#pragma unroll
    for (int r = 0; r < 16; ++r) { p1[r] = __expf(fmaf(sb[r], 0.125f, -m_new)); lsum += p1[r]; }
    lsum += __shfl_xor(lsum, 32);
    l_run = fmaf(l_run, alpha, lsum);
    m_run = m_new;
#pragma unroll
    for (int r = 0; r < 16; ++r) { Oa[r] *= alpha; Ob[r] *= alpha; }

    unsigned bw[2][2][4];
#define REDIST(pb, kb_)                                                  \
    {                                                                    \
      unsigned t0_, t1_, t2_, t3_, t4_, t5_, t6_, t7_;                   \
      CVTPK(t0_, pb[0], pb[1]);   CVTPK(t1_, pb[2], pb[3]);              \
      CVTPK(t2_, pb[4], pb[5]);   CVTPK(t3_, pb[6], pb[7]);              \
      CVTPK(t4_, pb[8], pb[9]);   CVTPK(t5_, pb[10], pb[11]);            \
      CVTPK(t6_, pb[12], pb[13]); CVTPK(t7_, pb[14], pb[15]);            \
      swap32(t0_, t2_, lane); swap32(t1_, t3_, lane);                    \
      swap32(t4_, t6_, lane); swap32(t5_, t7_, lane);                    \
      bw[kb_][0][0] = t0_; bw[kb_][0][1] = t1_; bw[kb_][0][2] = t2_;     \
      bw[kb_][0][3] = t3_;                                               \
      bw[kb_][1][0] = t4_; bw[kb_][1][1] = t5_; bw[kb_][1][2] = t6_;     \
      bw[kb_][1][3] = t7_;                                               \
    }
    REDIST(p0, 0)
    REDIST(p1, 1)
#undef REDIST

    const unsigned* vbr = &vt[kt & 1][0];
#pragma unroll
    for (int kb = 0; kb < 2; ++kb)
#pragma unroll
      for (int st = 0; st < 2; ++st) {
        const u32x4 pw = { bw[kb][st][0], bw[kb][st][1], bw[kb][st][2], bw[kb][st][3] };
        const bf16x8 pf = __builtin_bit_cast(bf16x8, pw);
        {
          const int row = c;
          const int off = (row * 128 + (kb * 64 + st * 32 + g * 16)) ^ ((row & 7) << 4);
          const bf16x8 va = __builtin_bit_cast(bf16x8, *(const u32x4*)((const char*)vbr + off));
          Oa = __builtin_amdgcn_mfma_f32_32x32x16_bf16(va, pf, Oa, 0, 0, 0);
        }
        {
          const int row = 32 + c;
          const int off = (row * 128 + (kb * 64 + st * 32 + g * 16)) ^ ((row & 7) << 4);
          const bf16x8 va = __builtin_bit_cast(bf16x8, *(const u32x4*)((const char*)vbr + off));
          Ob = __builtin_amdgcn_mfma_f32_32x32x16_bf16(va, pf, Ob, 0, 0, 0);
        }
      }

    v0 = v0n; v1 = v1n;
  }

  const float inv = 1.f / l_run;
  __hip_bfloat16* drow = att + base + (size_t)(q0 + c) * 64;
#pragma unroll
  for (int qd = 0; qd < 4; ++qd) {
    unsigned lo, hi2;
    {
      const float a0 = Oa[4 * qd + 0] * inv, a1 = Oa[4 * qd + 1] * inv;
      const float a2 = Oa[4 * qd + 2] * inv, a3 = Oa[4 * qd + 3] * inv;
      CVTPK(lo, a0, a1); CVTPK(hi2, a2, a3);
      uint2 w; w.x = lo; w.y = hi2;
      *(uint2*)(drow + 8 * qd + 4 * g) = w;
    }
    {
      const float a0 = Ob[4 * qd + 0] * inv, a1 = Ob[4 * qd + 1] * inv;
      const float a2 = Ob[4 * qd + 2] * inv, a3 = Ob[4 * qd + 3] * inv;
      CVTPK(lo, a0, a1); CVTPK(hi2, a2, a3);
      uint2 w; w.x = lo; w.y = hi2;
      *(uint2*)(drow + 32 + 8 * qd + 4 * g) = w;
    }
  }
}

// =====================================================================
// Launch
// =====================================================================
extern "C" void kernel_launch(void* const* d_in, const int* in_sizes, int n_in,
                              void* d_out, int out_size, void* d_ws, size_t ws_size,
                              hipStream_t stream) {
  const float* x      = (const float*)d_in[0];
  const float* loc_wq = (const float*)d_in[1];
  const float* loc_bq = (const float*)d_in[2];
  const float* loc_wk = (const float*)d_in[3];
  const float* loc_bk = (const float*)d_in[4];
  const float* loc_wv = (const float*)d_in[5];
  const float* loc_bv = (const float*)d_in[6];
  const float* loc_wo = (const float*)d_in[7];
  const float* loc_bo = (const float*)d_in[8];
  const float* g_wq  = (const float*)d_in[9];
  const float* g_bq  = (const float*)d_in[10];
  const float* g_wk  = (const float*)d_in[11];
  const float* g_bk  = (const float*)d_in[12];
  const float* g_wv  = (const float*)d_in[13];
  const float* g_bv  = (const float*)d_in[14];
  const float* g_wo  = (const float*)d_in[15];
  const float* g_bo  = (const float*)d_in[16];
  const float* out_w = (const float*)d_in[17];
  const float* out_b = (const float*)d_in[18];
  float* out = (float*)d_out;

  __hip_bfloat16* wsb = (__hip_bfloat16*)d_ws;
  const size_t SZ = (size_t)8192 * 512;
  const size_t MS = (size_t)512 * 512;
  // WT slots: 0-8 loc qkv, 9-11 g qkv, 12-15 outw^T, 16-18 loc_wo (plain),
  //           19 g_wo (plain), 20-23 Wfused^T
  __hip_bfloat16* xb    = wsb;
  __hip_bfloat16* WT    = wsb + SZ;
  __hip_bfloat16* Xq    = wsb + SZ + 24 * MS;
  __hip_bfloat16* Xk    = Xq + SZ;
  __hip_bfloat16* Xv    = Xq + 2 * SZ;
  __hip_bfloat16* abar0 = Xq + 3 * SZ;
  __hip_bfloat16* abar1 = Xq + 4 * SZ;
  __hip_bfloat16* abar2 = Xq + 5 * SZ;
  __hip_bfloat16* abar3 = Xq + 6 * SZ;
  float* bfused = (float*)(Xq + 7 * SZ);                  // 4 x 512 fp32
  __hip_bfloat16* bqkvb = (__hip_bfloat16*)(bfused + 2048); // 9 x 512 bf16
  __hip_bfloat16* abars[3] = {abar0, abar1, abar2};

  const dim3 thr(256);

  // ---- one-time prep ----
  cast_x_kernel<<<2048, thr, 0, stream>>>(x, xb);
  prep_weights_kernel<<<dim3(256, 20), thr, 0, stream>>>(
      loc_wq, loc_wk, loc_wv, g_wq, g_wk, g_wv, out_w, loc_wo, g_wo, WT);
  cast_biases_kernel<<<18, thr, 0, stream>>>(loc_bq, loc_bk, loc_bv, bqkvb);
  gemm_fusew_kernel<<<dim3(4, 8, 4), thr, 0, stream>>>(WT + 12 * MS, WT + 16 * MS,
                                                       WT + 20 * MS);
  bias_fuse_kernel<<<dim3(2, 4), thr, 0, stream>>>(loc_bo, g_bo, out_w, out_b, bfused);

  const dim3 ggrid(4, 128);
  const dim3 gqkv(4, 128, 3);

  for (int lv = 0; lv < 3; ++lv) {
    gemm_qkv_kernel<<<gqkv, thr, 0, stream>>>(
        xb, WT + lv * MS, 3 * MS,
        loc_bq + lv * 512, loc_bk + lv * 512, loc_bv + lv * 512, Xq);

    const __hip_bfloat16* bqb = bqkvb + (lv * 3 + 0) * 512;
    const __hip_bfloat16* bkb = bqkvb + (lv * 3 + 1) * 512;
    const __hip_bfloat16* bvb = bqkvb + (lv * 3 + 2) * 512;
    if (lv == 0)
      local_attn_mfma_kernel<3><<<2048, thr, 0, stream>>>(Xq, Xk, Xv, bqb, bkb, bvb, abars[lv]);
    else if (lv == 1)
      local_attn_mfma_kernel<5><<<2048, thr, 0, stream>>>(Xq, Xk, Xv, bqb, bkb, bvb, abars[lv]);
    else
      local_attn_mfma_kernel<7><<<2048, thr, 0, stream>>>(Xq, Xk, Xv, bqb, bkb, bvb, abars[lv]);
  }

  // global branch
  gemm_qkv_kernel<<<gqkv, thr, 0, stream>>>(xb, WT + 9 * MS, MS, g_bq, g_bk, g_bv, Xq);
  global_attn_mfma_kernel<<<dim3(8, 64), thr, 0, stream>>>(Xq, Xk, Xv, abar3);

  // fused output projection: one K=2048 GEMM, out written once
  gemm_out_fused_kernel<<<ggrid, thr, 0, stream>>>(abar0, abar1, abar2, abar3,
                                                   WT + 20 * MS, bfused, out);
}